// Round 5
// baseline (260.713 us; speedup 1.0000x reference)
//
#include <hip/hip_runtime.h>

// LinearAttention, fp16-MFMA restructuring (round 8).
//   xT   = transpose+cvt(x)          [b][l][c] f16   (B-operand for K1,K5)
//   kv   = wkvT @ xT^T  (MFMA)       [b][f][l] f16, f<512:k, f>=512:v
//   k    = softmax_L(k)              in place, f16
//   ctxP = v k^T partials (MFMA, K split 16)  [s][bh][e*64+d] f32
//   a2tT = (sum_s ctxP . w_out)^T    [b][c][g] f16  (k-fast for M-build)
//   Mf   = a2tT @ wqs^T (MFMA)       [b][c][c'] f16 = A-operand of K5
//   out  = Mf @ xT^T + b_out (MFMA, fp32 out)
// Round-8: 256x256/128KB-LDS gemm256 (1 block/CU -> prologue fill and
// store-drain epilogue fully serialized per block; K5 @ 51us with HALF of
// K1's FLOPs exposed this) replaced by gemm128: 128x128, BK=64, 8 waves,
// SINGLE 32KB LDS buffer, __launch_bounds__(512,4) -> 2 blocks/CU.
// Inter-block TLP (m114) overlaps staging latency + epilogue writes with
// the co-resident block's MFMAs. T1 XCD swizzle + T2 source-swizzle kept
// (bank conflicts measured 0). setprio/asm-ds_read removed (no in-flight
// LDS-DMA at read time -> no alias hazard; lockstep setprio ~neutral).

typedef _Float16 half2_t __attribute__((ext_vector_type(2)));
typedef _Float16 half4_t __attribute__((ext_vector_type(4)));
typedef _Float16 half8_t __attribute__((ext_vector_type(8)));
typedef float    floatx4 __attribute__((ext_vector_type(4)));

#define SCALE_ 0.125f
#define CSPLIT 16

__device__ __forceinline__ void async_lds16(const _Float16* g, _Float16* l) {
    __builtin_amdgcn_global_load_lds(
        (const __attribute__((address_space(1))) void*)g,
        (__attribute__((address_space(3))) void*)l,
        16, 0, 0);
}

#define VMW0() asm volatile("s_waitcnt vmcnt(0)" ::: "memory")

// ---------------- 128x128 MFMA GEMM, single-buffer, 2 blocks/CU ------------
// C[m][n] = sum_k A[m][k]*B[n][k] (+bias[m]).  A:[M][K] k-fast, B:[N][K]
// k-fast, C:[M][N].  Requires M%128==0, N%128==0, K%64==0, grid blocks %8==0.
template <typename OutT>
__global__ __launch_bounds__(512, 4)
void gemm128(const _Float16* __restrict__ A, long aBatch, int K,
             const _Float16* __restrict__ B, long bBatch,
             OutT* __restrict__ C, int ldc, long cBatch,
             const float* __restrict__ bias)
{
    // 32 KB: A[128][64] f16 at 0, B[128][64] f16 at elem 8192
    __shared__ _Float16 smem[16384];
    const int tid  = threadIdx.x;
    const int lane = tid & 63;
    const int wave = tid >> 6;
    const int wm = (wave & 3) * 32;    // 4-way M split
    const int wn = (wave >> 2) * 64;   // 2-way N split

    // T1: XCD swizzle (bijective: nwg % 8 == 0 for all our launches).
    const int nx = gridDim.x, ny = gridDim.y;
    const int nwg = nx * ny * gridDim.z;
    const int bid = blockIdx.x + nx * (blockIdx.y + ny * blockIdx.z);
    const int per = nwg >> 3;
    const int wg  = (bid & 7) * per + (bid >> 3);
    const int yb = wg % ny;
    const int xb = (wg / ny) % nx;
    const int zb = wg / (ny * nx);

    const int m0 = yb * 128;
    const int n0 = xb * 128;
    const long bz = zb;

    // staging map: row = tid>>3 (64 rows/instr), phys granule tid&7 (8 elems)
    // T2: inverse-swizzled SOURCE (rule #21): phys granule g at row r holds
    // logical granule g^(r&7); LDS dest stays linear for global_load_lds.
    const int srow = tid >> 3;
    const int sxor = (((tid & 7) ^ (srow & 7)) << 3);   // elems
    const _Float16* pA = A + bz * aBatch + (long)(m0 + srow) * K + sxor;
    const _Float16* pB = B + bz * bBatch + (long)(n0 + srow) * K + sxor;
    _Float16* ldst = &smem[tid * 8];

    // fragment read offsets (swizzled read side), element units
    const int fm  = lane & 15;
    const int fkg = lane >> 4;          // 0..3
    int aRow[2], bRow[4], gxo[2];
#pragma unroll
    for (int i = 0; i < 2; ++i) aRow[i] = (wm + i * 16 + fm) << 6;
#pragma unroll
    for (int j = 0; j < 4; ++j) bRow[j] = 8192 + ((wn + j * 16 + fm) << 6);
#pragma unroll
    for (int k = 0; k < 2; ++k) gxo[k] = (((k * 4 + fkg) ^ (fm & 7)) << 3);

    floatx4 acc[2][4];
#pragma unroll
    for (int i = 0; i < 2; ++i)
#pragma unroll
        for (int j = 0; j < 4; ++j) acc[i][j] = (floatx4)0.0f;

    for (int t = 0; t < (K >> 6); ++t) {
        __syncthreads();               // prev tile's LDS reads done everywhere
        async_lds16(pA + t * 64,                  ldst);
        async_lds16(pA + 64 * (long)K + t * 64,   ldst + 4096);
        async_lds16(pB + t * 64,                  ldst + 8192);
        async_lds16(pB + 64 * (long)K + t * 64,   ldst + 12288);
        VMW0();                        // own loads landed (wave-symmetric)
        __syncthreads();               // => all waves' loads landed

        half8_t aF[4], bF[8];
#pragma unroll
        for (int i = 0; i < 2; ++i)
#pragma unroll
            for (int k = 0; k < 2; ++k)
                aF[i * 2 + k] = *(const half8_t*)&smem[aRow[i] + gxo[k]];
#pragma unroll
        for (int j = 0; j < 4; ++j)
#pragma unroll
            for (int k = 0; k < 2; ++k)
                bF[j * 2 + k] = *(const half8_t*)&smem[bRow[j] + gxo[k]];
#pragma unroll
        for (int i = 0; i < 2; ++i)
#pragma unroll
            for (int j = 0; j < 4; ++j)
#pragma unroll
                for (int k = 0; k < 2; ++k)
                    acc[i][j] = __builtin_amdgcn_mfma_f32_16x16x32_f16(
                        aF[i * 2 + k], bF[j * 2 + k], acc[i][j], 0, 0, 0);
    }

    // C/D layout: n = lane&15, m = (lane>>4)*4 + reg   [m89/m91-verified]
    const int em = (lane >> 4) * 4;
    const int en = lane & 15;
    OutT* Cb = C + bz * cBatch;
#pragma unroll
    for (int i = 0; i < 2; ++i) {
#pragma unroll
        for (int r = 0; r < 4; ++r) {
            const int m = m0 + wm + i * 16 + em + r;
            const float bi = bias ? bias[m] : 0.0f;
#pragma unroll
            for (int j = 0; j < 4; ++j) {
                const int n = n0 + wn + j * 16 + en;
                Cb[(long)m * ldc + n] = (OutT)(acc[i][j][r] + bi);
            }
        }
    }
}

// ---------------- context via MFMA: ctxP[s][bh][e*64+d] --------------------
__global__ __launch_bounds__(256)
void context_mfma(const _Float16* __restrict__ kv, float* __restrict__ ctxP)
{
    const int bh = blockIdx.y;             // 0..63
    const int b = bh >> 3, h = bh & 7;
    const int l0 = blockIdx.x * (4096 / CSPLIT);   // 256-wide l slab
    const _Float16* vbase = kv + (long)b * 4194304 + (long)(512 + h * 64) * 4096;
    const _Float16* kbase = kv + (long)b * 4194304 + (long)(h * 64) * 4096;

    __shared__ _Float16 As[64 * 32];   // v tile [e][32]
    __shared__ _Float16 Bs[64 * 32];   // k tile [d][32]
    const int tid  = threadIdx.x;
    const int lane = tid & 63;
    const int wave = tid >> 6;
    const int sr = tid >> 2;
    const int sc = (tid & 3) * 8;
    const int wm = (wave & 1) * 32;
    const int wn = (wave >> 1) * 32;
    const int fm = lane & 15;
    const int fk = (lane >> 4) * 8;

    floatx4 acc[2][2];
#pragma unroll
    for (int i = 0; i < 2; ++i)
#pragma unroll
        for (int j = 0; j < 2; ++j) acc[i][j] = (floatx4)0.0f;

    for (int k0 = 0; k0 < 4096 / CSPLIT; k0 += 32) {
        __syncthreads();
        async_lds16(vbase + (long)sr * 4096 + l0 + k0 + sc, &As[tid * 8]);
        async_lds16(kbase + (long)sr * 4096 + l0 + k0 + sc, &Bs[tid * 8]);
        __syncthreads();

        half8_t a[2], b2[2];
#pragma unroll
        for (int i = 0; i < 2; ++i)
            a[i] = *(const half8_t*)&As[(wm + i * 16 + fm) * 32 + fk];
#pragma unroll
        for (int j = 0; j < 2; ++j)
            b2[j] = *(const half8_t*)&Bs[(wn + j * 16 + fm) * 32 + fk];
#pragma unroll
        for (int i = 0; i < 2; ++i)
#pragma unroll
            for (int j = 0; j < 2; ++j)
                acc[i][j] = __builtin_amdgcn_mfma_f32_16x16x32_f16(
                    a[i], b2[j], acc[i][j], 0, 0, 0);
    }

    const int em = (lane >> 4) * 4;
    const int en = lane & 15;
    float* base = ctxP + ((long)blockIdx.x * 64 + bh) * 4096;
#pragma unroll
    for (int i = 0; i < 2; ++i)
#pragma unroll
        for (int r = 0; r < 4; ++r)
#pragma unroll
            for (int j = 0; j < 2; ++j)
                base[(wm + i * 16 + em + r) * 64 + wn + j * 16 + en] = acc[i][j][r];
}

// ---------------- transpose + fp32->fp16 convert ---------------------------
__global__ __launch_bounds__(256)
void transpose_cvt(const float* __restrict__ src, int ld_s, long sB,
                   _Float16* __restrict__ dst, int ld_d, long dB)
{
    __shared__ float tile[64][65];
    const int c0 = blockIdx.x * 64;
    const int r0 = blockIdx.y * 64;
    const float* S = src + (long)blockIdx.z * sB;
    _Float16* D = dst + (long)blockIdx.z * dB;
    const int t = threadIdx.x;
    const int lr = t >> 4;
    const int lc = (t & 15) * 4;
#pragma unroll
    for (int i = 0; i < 4; ++i) {
        const float4 v = *(const float4*)(S + (long)(r0 + lr + 16 * i) * ld_s + c0 + lc);
        tile[lr + 16 * i][lc + 0] = v.x;
        tile[lr + 16 * i][lc + 1] = v.y;
        tile[lr + 16 * i][lc + 2] = v.z;
        tile[lr + 16 * i][lc + 3] = v.w;
    }
    __syncthreads();
    const int rl = (t & 15) * 4;
    const int cl = t >> 4;
#pragma unroll
    for (int i = 0; i < 4; ++i) {
        const int c = cl + 16 * i;
        half4_t o;
        o[0] = (_Float16)tile[rl + 0][c];
        o[1] = (_Float16)tile[rl + 1][c];
        o[2] = (_Float16)tile[rl + 2][c];
        o[3] = (_Float16)tile[rl + 3][c];
        *(half4_t*)(D + (long)(c0 + c) * ld_d + r0 + rl) = o;
    }
}

// ---------------- wqs[c'][g] = SCALE * w_qkv[c'][g], f16 -------------------
__global__ __launch_bounds__(256)
void scale_wq_kernel(const float* __restrict__ w_qkv, _Float16* __restrict__ wqs)
{
    const int c = blockIdx.x;
    const int t = threadIdx.x;
    const float2 v = *(const float2*)(w_qkv + (long)c * 1536 + t * 2);
    half2_t o;
    o[0] = (_Float16)(v.x * SCALE_);
    o[1] = (_Float16)(v.y * SCALE_);
    *(half2_t*)(wqs + (long)c * 512 + t * 2) = o;
}

// ---------------- softmax over L per (b, f<512) row, f16 in place ----------
__global__ __launch_bounds__(256)
void softmax_rows_h(_Float16* __restrict__ kv)
{
    const int row = blockIdx.x;            // 0..4095
    const int b = row >> 9, f = row & 511;
    _Float16* p = kv + (long)b * 4194304 + (long)f * 4096;
    const int tid = threadIdx.x;

    half8_t h0 = *(const half8_t*)(p + tid * 16);
    half8_t h1 = *(const half8_t*)(p + tid * 16 + 8);
    float v[16];
#pragma unroll
    for (int i = 0; i < 8; ++i) { v[i] = (float)h0[i]; v[8 + i] = (float)h1[i]; }

    float mx = -3.4e38f;
#pragma unroll
    for (int i = 0; i < 16; ++i) mx = fmaxf(mx, v[i]);
#pragma unroll
    for (int off = 32; off > 0; off >>= 1)
        mx = fmaxf(mx, __shfl_down(mx, off));

    __shared__ float red[8];
    if ((tid & 63) == 0) red[tid >> 6] = mx;
    __syncthreads();
    mx = fmaxf(fmaxf(red[0], red[1]), fmaxf(red[2], red[3]));

    float s = 0.0f;
#pragma unroll
    for (int i = 0; i < 16; ++i) { v[i] = __expf(v[i] - mx); s += v[i]; }
#pragma unroll
    for (int off = 32; off > 0; off >>= 1)
        s += __shfl_down(s, off);
    if ((tid & 63) == 0) red[4 + (tid >> 6)] = s;
    __syncthreads();
    const float inv = 1.0f / (red[4] + red[5] + red[6] + red[7]);

#pragma unroll
    for (int i = 0; i < 8; ++i) {
        h0[i] = (_Float16)(v[i] * inv);
        h1[i] = (_Float16)(v[8 + i] * inv);
    }
    *(half8_t*)(p + tid * 16) = h0;
    *(half8_t*)(p + tid * 16 + 8) = h1;
}

// ---- a2tT[b][c][g] = (sum_e (sum_s ctxP)[e][d] w_out[(h,e),c])^T, f16 -----
__global__ __launch_bounds__(256)
void a2t_kernel(const float* __restrict__ ctxP, const float* __restrict__ w_out,
                _Float16* __restrict__ a2tT)
{
    const int ct = blockIdx.x, h = blockIdx.y, b = blockIdx.z;
    __shared__ float cs[64][64];      // cs[e][d]
    __shared__ float wsh[64][128];    // wsh[e][c]
    __shared__ _Float16 so[128][64];  // so[c_local][d]
    const int tid = threadIdx.x;
    {
        const int lr = tid >> 4, lc4 = (tid & 15) * 4;
        floatx4 accv[4];
#pragma unroll
        for (int i = 0; i < 4; ++i) accv[i] = (floatx4)0.0f;
        for (int s = 0; s < CSPLIT; ++s) {
            const float* cbase = ctxP + ((long)s * 64 + b * 8 + h) * 4096;
#pragma unroll
            for (int i = 0; i < 4; ++i)
                accv[i] += *(const floatx4*)(cbase + (lr + 16 * i) * 64 + lc4);
        }
#pragma unroll
        for (int i = 0; i < 4; ++i)
            *(floatx4*)&cs[lr + 16 * i][lc4] = accv[i];

        const float* wbase = w_out + (long)(h * 64) * 512 + ct * 128;
        const int wr = tid >> 5, wc4 = (tid & 31) * 4;
#pragma unroll
        for (int i = 0; i < 8; ++i) {
            const int e = wr + 8 * i;
            *(float4*)&wsh[e][wc4] = *(const float4*)(wbase + (long)e * 512 + wc4);
        }
    }
    __syncthreads();
    const int tx = tid & 15, ty = tid >> 4;
    float acc[4][8] = {};
    for (int e = 0; e < 64; ++e) {
        float a[4], bv[8];
#pragma unroll
        for (int i = 0; i < 4; ++i) a[i] = cs[e][ty * 4 + i];
#pragma unroll
        for (int j = 0; j < 8; ++j) bv[j] = wsh[e][tx * 8 + j];
#pragma unroll
        for (int i = 0; i < 4; ++i)
#pragma unroll
            for (int j = 0; j < 8; ++j)
                acc[i][j] = fmaf(a[i], bv[j], acc[i][j]);
    }
#pragma unroll
    for (int i = 0; i < 4; ++i)
#pragma unroll
        for (int j = 0; j < 8; ++j)
            so[tx * 8 + j][ty * 4 + i] = (_Float16)acc[i][j];
    __syncthreads();
#pragma unroll
    for (int q = tid; q < 1024; q += 256) {
        const int c_local = q >> 3, co = (q & 7) * 8;
        *(half8_t*)(a2tT + (long)b * 262144 + (long)(ct * 128 + c_local) * 512
                    + h * 64 + co) = *(const half8_t*)&so[c_local][co];
    }
}

extern "C" void kernel_launch(void* const* d_in, const int* in_sizes, int n_in,
                              void* d_out, int out_size, void* d_ws, size_t ws_size,
                              hipStream_t stream)
{
    const float* x      = (const float*)d_in[0];   // (8,512,4096)
    const float* w_qkv  = (const float*)d_in[1];   // (512,1536)
    const float* w_out  = (const float*)d_in[2];   // (512,512)
    const float* b_out  = (const float*)d_in[3];   // (512,)
    float* out = (float*)d_out;                    // (8,512,4096)

    char* wsb = (char*)d_ws;                       // ~122 MB total
    _Float16* kv   = (_Float16*)(wsb);             // 64 MB  [b][f][l]
    _Float16* xT   = (_Float16*)(wsb + 67108864);  // 32 MB  [b][l][c]
    _Float16* wkvT = (_Float16*)(wsb + 100663296); // 1 MB   [f][c]
    _Float16* wqs  = (_Float16*)(wsb + 101711872); // 0.5 MB [c'][g]
    _Float16* a2tT = (_Float16*)(wsb + 102236160); // 4 MB   [b][c][g]
    _Float16* mf   = (_Float16*)(wsb + 106430464); // 4 MB   [b][c][c']
    float*    ctxP = (float*)   (wsb + 110624768); // 16 MB  [s][bh][e*64+d]

    // xT = transpose+cvt(x): src rows c=512, cols l=4096
    transpose_cvt<<<dim3(64, 8, 8), 256, 0, stream>>>(
        x, 4096, 2097152L, xT, 512, 2097152L);
    // wkvT[f][c]: src rows c=512 (ld 1536, offset 512), cols f=1024
    transpose_cvt<<<dim3(16, 8, 1), 256, 0, stream>>>(
        w_qkv + 512, 1536, 0L, wkvT, 512, 0L);
    // wqs[c'][g] = SCALE * w_qkv[c'][g]
    scale_wq_kernel<<<dim3(512), 256, 0, stream>>>(w_qkv, wqs);

    // K1: kv[b][f][l] = sum_c wkvT[f][c] * xT[b][l][c]   (M=1024,N=4096,K=512)
    gemm128<_Float16><<<dim3(32, 8, 8), 512, 0, stream>>>(
        wkvT, 0L, 512, xT, 2097152L, kv, 4096, 4194304L, nullptr);

    // K2: softmax over L on the k half
    softmax_rows_h<<<dim3(4096), 256, 0, stream>>>(kv);

    // K3: context partials via MFMA
    context_mfma<<<dim3(CSPLIT, 64), 256, 0, stream>>>(kv, ctxP);

    // K4a: a2tT (reduces the CSPLIT partials on load)
    a2t_kernel<<<dim3(4, 8, 8), 256, 0, stream>>>(ctxP, w_out, a2tT);

    // K4m: mf[b][c][c'] = sum_g a2tT[b][c][g] * wqs[c'][g]   (= M^T, f16)
    gemm128<_Float16><<<dim3(4, 4, 8), 512, 0, stream>>>(
        a2tT, 262144L, 512, wqs, 0L, mf, 512, 262144L, nullptr);

    // K5: out[b][c][l] = sum_c' mf[b][c][c'] * xT[b][l][c'] + b_out[c]
    //     (M=512,N=4096,K=512)
    gemm128<float><<<dim3(32, 4, 8), 512, 0, stream>>>(
        mf, 262144L, 512, xT, 2097152L, out, 4096, 2097152L, b_out);
}

// Round 6
// 246.742 us; speedup vs baseline: 1.0566x; 1.0566x over previous
//
#include <hip/hip_runtime.h>

// LinearAttention, fp16-MFMA restructuring (round 9).
//   xT   = transpose+cvt(x)          [b][l][c] f16   (B-operand for K1,K5)
//   kv   = wkvT @ xT^T  (MFMA)       [b][f][l] f16, f<512:k, f>=512:v  (RAW k)
//   stat = per-row {max, 1/sum(exp)} of k       (k_stats, 32 KB)
//   ctxP = v softmax(k)^T partials (MFMA, K split 16)  [s][bh][e*64+d] f32
//          -- exp((k-mx))*inv applied IN-KERNEL during staging (fused)
//   a2tT = (sum_s ctxP . w_out)^T    [b][c][g] f16  (k-fast for M-build)
//   Mf   = a2tT @ wqs^T (MFMA)       [b][c][c'] f16 = A-operand of K5
//   out  = Mf @ xT^T + b_out (MFMA, fp32 out)
// Round-9 (pivot to non-GEMM chain; GEMMs frozen after 4 structure rounds
// all landed 50-52us regardless of occupancy 17-47% / barriers / vmcnt):
//  * softmax_rows_h (64MB RW pass) REMOVED; k_stats writes {mx,inv}/row
//    (bitwise-same reduction order); context applies exp on the fly.
//  * context_mfma: both operands reg-staged (global->reg->ds_write),
//    LDS rows padded 32->40 elems: old 64B-row [64][32] tiles were an
//    ~8-way bank conflict on ds_read_b128 (the 4.19M-conflict pattern);
//    80B rows rotate banks over 8 rows -> <=2-way (free).
//  * stats buffer aliases a2tT region (dead between K1 and a2t).

typedef _Float16 half2_t __attribute__((ext_vector_type(2)));
typedef _Float16 half4_t __attribute__((ext_vector_type(4)));
typedef _Float16 half8_t __attribute__((ext_vector_type(8)));
typedef float    floatx4 __attribute__((ext_vector_type(4)));

#define SCALE_ 0.125f
#define CSPLIT 16

__device__ __forceinline__ void async_lds16(const _Float16* g, _Float16* l) {
    __builtin_amdgcn_global_load_lds(
        (const __attribute__((address_space(1))) void*)g,
        (__attribute__((address_space(3))) void*)l,
        16, 0, 0);
}

#define VMW0() asm volatile("s_waitcnt vmcnt(0)" ::: "memory")

// ---------------- 128x128 MFMA GEMM, single-buffer, 2 blocks/CU ------------
// C[m][n] = sum_k A[m][k]*B[n][k] (+bias[m]).  A:[M][K] k-fast, B:[N][K]
// k-fast, C:[M][N].  Requires M%128==0, N%128==0, K%64==0, grid blocks %8==0.
// FROZEN since round 8 (best-known GEMM form for these shapes).
template <typename OutT>
__global__ __launch_bounds__(512, 4)
void gemm128(const _Float16* __restrict__ A, long aBatch, int K,
             const _Float16* __restrict__ B, long bBatch,
             OutT* __restrict__ C, int ldc, long cBatch,
             const float* __restrict__ bias)
{
    // 32 KB: A[128][64] f16 at 0, B[128][64] f16 at elem 8192
    __shared__ _Float16 smem[16384];
    const int tid  = threadIdx.x;
    const int lane = tid & 63;
    const int wave = tid >> 6;
    const int wm = (wave & 3) * 32;    // 4-way M split
    const int wn = (wave >> 2) * 64;   // 2-way N split

    // T1: XCD swizzle (bijective: nwg % 8 == 0 for all our launches).
    const int nx = gridDim.x, ny = gridDim.y;
    const int nwg = nx * ny * gridDim.z;
    const int bid = blockIdx.x + nx * (blockIdx.y + ny * blockIdx.z);
    const int per = nwg >> 3;
    const int wg  = (bid & 7) * per + (bid >> 3);
    const int yb = wg % ny;
    const int xb = (wg / ny) % nx;
    const int zb = wg / (ny * nx);

    const int m0 = yb * 128;
    const int n0 = xb * 128;
    const long bz = zb;

    // staging map: row = tid>>3 (64 rows/instr), phys granule tid&7 (8 elems)
    // T2: inverse-swizzled SOURCE (rule #21): phys granule g at row r holds
    // logical granule g^(r&7); LDS dest stays linear for global_load_lds.
    const int srow = tid >> 3;
    const int sxor = (((tid & 7) ^ (srow & 7)) << 3);   // elems
    const _Float16* pA = A + bz * aBatch + (long)(m0 + srow) * K + sxor;
    const _Float16* pB = B + bz * bBatch + (long)(n0 + srow) * K + sxor;
    _Float16* ldst = &smem[tid * 8];

    // fragment read offsets (swizzled read side), element units
    const int fm  = lane & 15;
    const int fkg = lane >> 4;          // 0..3
    int aRow[2], bRow[4], gxo[2];
#pragma unroll
    for (int i = 0; i < 2; ++i) aRow[i] = (wm + i * 16 + fm) << 6;
#pragma unroll
    for (int j = 0; j < 4; ++j) bRow[j] = 8192 + ((wn + j * 16 + fm) << 6);
#pragma unroll
    for (int k = 0; k < 2; ++k) gxo[k] = (((k * 4 + fkg) ^ (fm & 7)) << 3);

    floatx4 acc[2][4];
#pragma unroll
    for (int i = 0; i < 2; ++i)
#pragma unroll
        for (int j = 0; j < 4; ++j) acc[i][j] = (floatx4)0.0f;

    for (int t = 0; t < (K >> 6); ++t) {
        __syncthreads();               // prev tile's LDS reads done everywhere
        async_lds16(pA + t * 64,                  ldst);
        async_lds16(pA + 64 * (long)K + t * 64,   ldst + 4096);
        async_lds16(pB + t * 64,                  ldst + 8192);
        async_lds16(pB + 64 * (long)K + t * 64,   ldst + 12288);
        VMW0();                        // own loads landed (wave-symmetric)
        __syncthreads();               // => all waves' loads landed

        half8_t aF[4], bF[8];
#pragma unroll
        for (int i = 0; i < 2; ++i)
#pragma unroll
            for (int k = 0; k < 2; ++k)
                aF[i * 2 + k] = *(const half8_t*)&smem[aRow[i] + gxo[k]];
#pragma unroll
        for (int j = 0; j < 4; ++j)
#pragma unroll
            for (int k = 0; k < 2; ++k)
                bF[j * 2 + k] = *(const half8_t*)&smem[bRow[j] + gxo[k]];
#pragma unroll
        for (int i = 0; i < 2; ++i)
#pragma unroll
            for (int j = 0; j < 4; ++j)
#pragma unroll
                for (int k = 0; k < 2; ++k)
                    acc[i][j] = __builtin_amdgcn_mfma_f32_16x16x32_f16(
                        aF[i * 2 + k], bF[j * 2 + k], acc[i][j], 0, 0, 0);
    }

    // C/D layout: n = lane&15, m = (lane>>4)*4 + reg   [m89/m91-verified]
    const int em = (lane >> 4) * 4;
    const int en = lane & 15;
    OutT* Cb = C + bz * cBatch;
#pragma unroll
    for (int i = 0; i < 2; ++i) {
#pragma unroll
        for (int r = 0; r < 4; ++r) {
            const int m = m0 + wm + i * 16 + em + r;
            const float bi = bias ? bias[m] : 0.0f;
#pragma unroll
            for (int j = 0; j < 4; ++j) {
                const int n = n0 + wn + j * 16 + en;
                Cb[(long)m * ldc + n] = (OutT)(acc[i][j][r] + bi);
            }
        }
    }
}

// ---------------- k_stats: per-row {max, 1/sum(exp)} of the k half ---------
// Reduction order bitwise-identical to the removed softmax_rows_h.
__global__ __launch_bounds__(256)
void k_stats(const _Float16* __restrict__ kv, float2* __restrict__ stats)
{
    const int row = blockIdx.x;            // 0..4095
    const int b = row >> 9, f = row & 511;
    const _Float16* p = kv + (long)b * 4194304 + (long)f * 4096;
    const int tid = threadIdx.x;

    half8_t h0 = *(const half8_t*)(p + tid * 16);
    half8_t h1 = *(const half8_t*)(p + tid * 16 + 8);
    float v[16];
#pragma unroll
    for (int i = 0; i < 8; ++i) { v[i] = (float)h0[i]; v[8 + i] = (float)h1[i]; }

    float mx = -3.4e38f;
#pragma unroll
    for (int i = 0; i < 16; ++i) mx = fmaxf(mx, v[i]);
#pragma unroll
    for (int off = 32; off > 0; off >>= 1)
        mx = fmaxf(mx, __shfl_down(mx, off));

    __shared__ float red[8];
    if ((tid & 63) == 0) red[tid >> 6] = mx;
    __syncthreads();
    mx = fmaxf(fmaxf(red[0], red[1]), fmaxf(red[2], red[3]));

    float s = 0.0f;
#pragma unroll
    for (int i = 0; i < 16; ++i) s += __expf(v[i] - mx);
#pragma unroll
    for (int off = 32; off > 0; off >>= 1)
        s += __shfl_down(s, off);
    if ((tid & 63) == 0) red[4 + (tid >> 6)] = s;
    __syncthreads();
    if (tid == 0) {
        const float inv = 1.0f / (red[4] + red[5] + red[6] + red[7]);
        stats[row] = make_float2(mx, inv);
    }
}

// ---------------- context via MFMA, softmax fused: ctxP[s][bh][e*64+d] -----
// Per (bh, slab s): C[m=e][n=d] = sum_l v[e,l] p[d,l], p = exp(k-mx)*inv.
// Both operands reg-staged; LDS rows padded to 40 elems (80B) -> bank
// rotation kills the old 64B-row 8-way conflict.
#define CPAD 40
__global__ __launch_bounds__(256)
void context_mfma(const _Float16* __restrict__ kv,
                  const float2* __restrict__ stats,
                  float* __restrict__ ctxP)
{
    const int bh = blockIdx.y;             // 0..63
    const int b = bh >> 3, h = bh & 7;
    const int l0 = blockIdx.x * (4096 / CSPLIT);   // 256-wide l slab

    __shared__ _Float16 As[64 * CPAD];   // v tile [e][40]
    __shared__ _Float16 Bs[64 * CPAD];   // p tile [d][40]
    const int tid  = threadIdx.x;
    const int lane = tid & 63;
    const int wave = tid >> 6;
    const int sr = tid >> 2;           // staged row 0..63
    const int sc = (tid & 3) * 8;      // staged col 0..24
    const int wm = (wave & 1) * 32;
    const int wn = (wave >> 1) * 32;
    const int fm = lane & 15;
    const int fk = (lane >> 4) * 8;

    const _Float16* vg = kv + (long)b * 4194304 + (long)(512 + h * 64 + sr) * 4096 + l0 + sc;
    const _Float16* kg = kv + (long)b * 4194304 + (long)(h * 64 + sr) * 4096 + l0 + sc;
    const float2 st = stats[b * 512 + h * 64 + sr];   // this thread's k-row

    floatx4 acc[2][2];
#pragma unroll
    for (int i = 0; i < 2; ++i)
#pragma unroll
        for (int j = 0; j < 2; ++j) acc[i][j] = (floatx4)0.0f;

    for (int k0 = 0; k0 < 4096 / CSPLIT; k0 += 32) {
        const half8_t vv = *(const half8_t*)(vg + k0);
        const half8_t kk = *(const half8_t*)(kg + k0);
        half8_t pp;
#pragma unroll
        for (int j = 0; j < 8; ++j)
            pp[j] = (_Float16)(__expf((float)kk[j] - st.x) * st.y);
        __syncthreads();               // prev tile's ds_reads done
        *(half8_t*)&As[sr * CPAD + sc] = vv;
        *(half8_t*)&Bs[sr * CPAD + sc] = pp;
        __syncthreads();               // tile staged

        half8_t a[2], b2[2];
#pragma unroll
        for (int i = 0; i < 2; ++i)
            a[i] = *(const half8_t*)&As[(wm + i * 16 + fm) * CPAD + fk];
#pragma unroll
        for (int j = 0; j < 2; ++j)
            b2[j] = *(const half8_t*)&Bs[(wn + j * 16 + fm) * CPAD + fk];
#pragma unroll
        for (int i = 0; i < 2; ++i)
#pragma unroll
            for (int j = 0; j < 2; ++j)
                acc[i][j] = __builtin_amdgcn_mfma_f32_16x16x32_f16(
                    a[i], b2[j], acc[i][j], 0, 0, 0);
    }

    const int em = (lane >> 4) * 4;
    const int en = lane & 15;
    float* base = ctxP + ((long)blockIdx.x * 64 + bh) * 4096;
#pragma unroll
    for (int i = 0; i < 2; ++i)
#pragma unroll
        for (int r = 0; r < 4; ++r)
#pragma unroll
            for (int j = 0; j < 2; ++j)
                base[(wm + i * 16 + em + r) * 64 + wn + j * 16 + en] = acc[i][j][r];
}

// ---------------- transpose + fp32->fp16 convert ---------------------------
__global__ __launch_bounds__(256)
void transpose_cvt(const float* __restrict__ src, int ld_s, long sB,
                   _Float16* __restrict__ dst, int ld_d, long dB)
{
    __shared__ float tile[64][65];
    const int c0 = blockIdx.x * 64;
    const int r0 = blockIdx.y * 64;
    const float* S = src + (long)blockIdx.z * sB;
    _Float16* D = dst + (long)blockIdx.z * dB;
    const int t = threadIdx.x;
    const int lr = t >> 4;
    const int lc = (t & 15) * 4;
#pragma unroll
    for (int i = 0; i < 4; ++i) {
        const float4 v = *(const float4*)(S + (long)(r0 + lr + 16 * i) * ld_s + c0 + lc);
        tile[lr + 16 * i][lc + 0] = v.x;
        tile[lr + 16 * i][lc + 1] = v.y;
        tile[lr + 16 * i][lc + 2] = v.z;
        tile[lr + 16 * i][lc + 3] = v.w;
    }
    __syncthreads();
    const int rl = (t & 15) * 4;
    const int cl = t >> 4;
#pragma unroll
    for (int i = 0; i < 4; ++i) {
        const int c = cl + 16 * i;
        half4_t o;
        o[0] = (_Float16)tile[rl + 0][c];
        o[1] = (_Float16)tile[rl + 1][c];
        o[2] = (_Float16)tile[rl + 2][c];
        o[3] = (_Float16)tile[rl + 3][c];
        *(half4_t*)(D + (long)(c0 + c) * ld_d + r0 + rl) = o;
    }
}

// ---------------- wqs[c'][g] = SCALE * w_qkv[c'][g], f16 -------------------
__global__ __launch_bounds__(256)
void scale_wq_kernel(const float* __restrict__ w_qkv, _Float16* __restrict__ wqs)
{
    const int c = blockIdx.x;
    const int t = threadIdx.x;
    const float2 v = *(const float2*)(w_qkv + (long)c * 1536 + t * 2);
    half2_t o;
    o[0] = (_Float16)(v.x * SCALE_);
    o[1] = (_Float16)(v.y * SCALE_);
    *(half2_t*)(wqs + (long)c * 512 + t * 2) = o;
}

// ---- a2tT[b][c][g] = (sum_e (sum_s ctxP)[e][d] w_out[(h,e),c])^T, f16 -----
__global__ __launch_bounds__(256)
void a2t_kernel(const float* __restrict__ ctxP, const float* __restrict__ w_out,
                _Float16* __restrict__ a2tT)
{
    const int ct = blockIdx.x, h = blockIdx.y, b = blockIdx.z;
    __shared__ float cs[64][64];      // cs[e][d]
    __shared__ float wsh[64][128];    // wsh[e][c]
    __shared__ _Float16 so[128][64];  // so[c_local][d]
    const int tid = threadIdx.x;
    {
        const int lr = tid >> 4, lc4 = (tid & 15) * 4;
        floatx4 accv[4];
#pragma unroll
        for (int i = 0; i < 4; ++i) accv[i] = (floatx4)0.0f;
        for (int s = 0; s < CSPLIT; ++s) {
            const float* cbase = ctxP + ((long)s * 64 + b * 8 + h) * 4096;
#pragma unroll
            for (int i = 0; i < 4; ++i)
                accv[i] += *(const floatx4*)(cbase + (lr + 16 * i) * 64 + lc4);
        }
#pragma unroll
        for (int i = 0; i < 4; ++i)
            *(floatx4*)&cs[lr + 16 * i][lc4] = accv[i];

        const float* wbase = w_out + (long)(h * 64) * 512 + ct * 128;
        const int wr = tid >> 5, wc4 = (tid & 31) * 4;
#pragma unroll
        for (int i = 0; i < 8; ++i) {
            const int e = wr + 8 * i;
            *(float4*)&wsh[e][wc4] = *(const float4*)(wbase + (long)e * 512 + wc4);
        }
    }
    __syncthreads();
    const int tx = tid & 15, ty = tid >> 4;
    float acc[4][8] = {};
    for (int e = 0; e < 64; ++e) {
        float a[4], bv[8];
#pragma unroll
        for (int i = 0; i < 4; ++i) a[i] = cs[e][ty * 4 + i];
#pragma unroll
        for (int j = 0; j < 8; ++j) bv[j] = wsh[e][tx * 8 + j];
#pragma unroll
        for (int i = 0; i < 4; ++i)
#pragma unroll
            for (int j = 0; j < 8; ++j)
                acc[i][j] = fmaf(a[i], bv[j], acc[i][j]);
    }
#pragma unroll
    for (int i = 0; i < 4; ++i)
#pragma unroll
        for (int j = 0; j < 8; ++j)
            so[tx * 8 + j][ty * 4 + i] = (_Float16)acc[i][j];
    __syncthreads();
#pragma unroll
    for (int q = tid; q < 1024; q += 256) {
        const int c_local = q >> 3, co = (q & 7) * 8;
        *(half8_t*)(a2tT + (long)b * 262144 + (long)(ct * 128 + c_local) * 512
                    + h * 64 + co) = *(const half8_t*)&so[c_local][co];
    }
}

extern "C" void kernel_launch(void* const* d_in, const int* in_sizes, int n_in,
                              void* d_out, int out_size, void* d_ws, size_t ws_size,
                              hipStream_t stream)
{
    const float* x      = (const float*)d_in[0];   // (8,512,4096)
    const float* w_qkv  = (const float*)d_in[1];   // (512,1536)
    const float* w_out  = (const float*)d_in[2];   // (512,512)
    const float* b_out  = (const float*)d_in[3];   // (512,)
    float* out = (float*)d_out;                    // (8,512,4096)

    char* wsb = (char*)d_ws;                       // ~122 MB total
    _Float16* kv   = (_Float16*)(wsb);             // 64 MB  [b][f][l]
    _Float16* xT   = (_Float16*)(wsb + 67108864);  // 32 MB  [b][l][c]
    _Float16* wkvT = (_Float16*)(wsb + 100663296); // 1 MB   [f][c]
    _Float16* wqs  = (_Float16*)(wsb + 101711872); // 0.5 MB [c'][g]
    _Float16* a2tT = (_Float16*)(wsb + 102236160); // 4 MB   [b][c][g]
    _Float16* mf   = (_Float16*)(wsb + 106430464); // 4 MB   [b][c][c']
    float*    ctxP = (float*)   (wsb + 110624768); // 16 MB  [s][bh][e*64+d]
    // stats aliases a2tT's first 32 KB: written after K1, consumed by
    // context, then a2t overwrites the region (launch-ordered, same stream).
    float2*   stats = (float2*)a2tT;

    // xT = transpose+cvt(x): src rows c=512, cols l=4096
    transpose_cvt<<<dim3(64, 8, 8), 256, 0, stream>>>(
        x, 4096, 2097152L, xT, 512, 2097152L);
    // wkvT[f][c]: src rows c=512 (ld 1536, offset 512), cols f=1024
    transpose_cvt<<<dim3(16, 8, 1), 256, 0, stream>>>(
        w_qkv + 512, 1536, 0L, wkvT, 512, 0L);
    // wqs[c'][g] = SCALE * w_qkv[c'][g]
    scale_wq_kernel<<<dim3(512), 256, 0, stream>>>(w_qkv, wqs);

    // K1: kv[b][f][l] = sum_c wkvT[f][c] * xT[b][l][c]   (M=1024,N=4096,K=512)
    gemm128<_Float16><<<dim3(32, 8, 8), 512, 0, stream>>>(
        wkvT, 0L, 512, xT, 2097152L, kv, 4096, 4194304L, nullptr);

    // K2: per-row softmax stats of the k half (replaces full softmax pass)
    k_stats<<<dim3(4096), 256, 0, stream>>>(kv, stats);

    // K3: context partials via MFMA, softmax fused into staging
    context_mfma<<<dim3(CSPLIT, 64), 256, 0, stream>>>(kv, stats, ctxP);

    // K4a: a2tT (reduces the CSPLIT partials on load)
    a2t_kernel<<<dim3(4, 8, 8), 256, 0, stream>>>(ctxP, w_out, a2tT);

    // K4m: mf[b][c][c'] = sum_g a2tT[b][c][g] * wqs[c'][g]   (= M^T, f16)
    gemm128<_Float16><<<dim3(4, 4, 8), 512, 0, stream>>>(
        a2tT, 262144L, 512, wqs, 0L, mf, 512, 262144L, nullptr);

    // K5: out[b][c][l] = sum_c' mf[b][c][c'] * xT[b][l][c'] + b_out[c]
    //     (M=512,N=4096,K=512)
    gemm128<float><<<dim3(32, 4, 8), 512, 0, stream>>>(
        mf, 262144L, 512, xT, 2097152L, out, 4096, 2097152L, b_out);
}